// Round 2
// baseline (486.654 us; speedup 1.0000x reference)
//
#include <hip/hip_runtime.h>
#include <cstdint>

// SpikeFP64Sqrt: rows of 64 float pulses (MSB-first fp64 bits) -> sqrt via
// exponent-halving guess + 12 IEEE fp64 Newton iterations -> pulses out.
//
// Memory-bound: 256 MiB in + 256 MiB out. One wave handles 64 rows:
//  - pack:   lane i loads pulse i (coalesced dword), __ballot gives the
//            lane-ordered mask, brev64 -> MSB-first uint64, captured by lane==row.
//  - compute: per-lane bit-exact fp64 (contract off; HIP double '/' is IEEE
//            correctly rounded, matching the XLA-CPU reference).
//  - unpack: shfl row-word to all lanes, float4 stores (1 KiB/instr).

#pragma clang fp contract(off)   // no FMA contraction anywhere (bit-exact fp64)

static constexpr uint64_t kSqrt2Mant = 1865452045155277ULL;
static constexpr uint64_t kNanBits   = 0x7FF8000000000000ULL;
static constexpr uint64_t kInfBits   = 0x7FF0000000000000ULL;
static constexpr uint64_t kMantMask  = 0xFFFFFFFFFFFFFULL;

__global__ __launch_bounds__(256) void spike_fp64_sqrt_kernel(
    const float* __restrict__ x, float* __restrict__ out, int rows) {
  const int lane   = threadIdx.x & 63;
  const int waveId = (int)blockIdx.x * 4 + (threadIdx.x >> 6);
  const long long waveRow0 = (long long)waveId * 64;

  // ---- pack: 64 rows per wave, each lane ends up owning row (waveRow0+lane) ----
  uint64_t u = 0;
#pragma unroll
  for (int rr = 0; rr < 64; ++rr) {
    const long long row = waveRow0 + rr;
    float v = 0.0f;
    if (row < (long long)rows) v = x[row * 64 + lane];
    // ballot bit j = lane j's pulse = MSB-first bit (63-j)  ->  brev64
    unsigned long long m = __ballot(v > 0.5f);
    if (lane == rr) u = __brevll(m);
  }

  // ---- per-lane fp64 sqrt, bit-exact vs reference ----
  const double f = __longlong_as_double((long long)u);

  const int e_x    = (int)((u >> 52) & 0x7FF);
  const int e_real = e_x - 1023;                       // 11-bit two's complement
  const long long e_half = ((long long)e_real) >> 1;   // arithmetic shift = floor/2
  const uint64_t mant = ((e_real & 1) != 0) ? kSqrt2Mant : 0ULL;
  const uint64_t ybits = (((uint64_t)(e_half + 1023)) << 52) | mant;
  double y = __longlong_as_double((long long)ybits);

#pragma unroll
  for (int it = 0; it < 12; ++it) {
    y = 0.5 * (y + f / y);                             // IEEE fp64, no contraction
  }

  uint64_t r = (uint64_t)__double_as_longlong(y);
  const bool is_neg    = (u >> 63) != 0;
  const bool m_any     = (u & kMantMask) != 0;
  const bool e_all_one = (e_x == 0x7FF);
  const bool e_is_zero = (e_x == 0);
  if (is_neg) r = kNanBits;                            // same override order as ref
  if (e_all_one && m_any) r = kNanBits;
  if (e_all_one && !m_any && !is_neg) r = kInfBits;
  if (e_is_zero && !m_any) r = 0ULL;

  // ---- unpack: 4 rows / iteration, float4 stores ----
  const long long rl = (long long)r;
#pragma unroll
  for (int j = 0; j < 16; ++j) {
    const int srcRow = 4 * j + (lane >> 4);            // 0..63 within the wave
    const uint64_t b = (uint64_t)__shfl(rl, srcRow, 64);
    const int c0 = (lane & 15) * 4;                    // column of float4
    float4 o;
    o.x = (float)((b >> (63 - c0)) & 1ULL);
    o.y = (float)((b >> (62 - c0)) & 1ULL);
    o.z = (float)((b >> (61 - c0)) & 1ULL);
    o.w = (float)((b >> (60 - c0)) & 1ULL);
    const long long row = waveRow0 + srcRow;
    if (row < (long long)rows) {
      *reinterpret_cast<float4*>(out + row * 64 + c0) = o;
    }
  }
}

extern "C" void kernel_launch(void* const* d_in, const int* in_sizes, int n_in,
                              void* d_out, int out_size, void* d_ws, size_t ws_size,
                              hipStream_t stream) {
  const float* x = (const float*)d_in[0];
  float* out = (float*)d_out;
  const int rows = in_sizes[0] / 64;                   // 64 pulses per fp64
  const int rowsPerBlock = 256;                        // 4 waves * 64 rows
  const int grid = (rows + rowsPerBlock - 1) / rowsPerBlock;
  spike_fp64_sqrt_kernel<<<grid, 256, 0, stream>>>(x, out, rows);
}

// Round 3
// 430.247 us; speedup vs baseline: 1.1311x; 1.1311x over previous
//
#include <hip/hip_runtime.h>
#include <cstdint>

// SpikeFP64Sqrt: rows of 64 float pulses (MSB-first fp64 bits) -> sqrt via
// exponent-halving guess + 12 IEEE fp64 Newton iterations -> pulses out.
//
// R2 post-mortem: VGPR_Count=12 => compiler serialized the 64 pack loads
// (one vmcnt(0) wait per row, ~900cyc HBM latency each) -> latency-bound at
// 189us with VALUBusy 21% / HBM 26%. Fix: batch 32 independent loads into
// explicit registers before the 32 ballots (MLP 1 -> 32). Also load with
// lane^63 so ballot yields the MSB-first word directly (no brev).

#pragma clang fp contract(off)   // no FMA contraction anywhere (bit-exact fp64)

static constexpr uint64_t kSqrt2Mant = 1865452045155277ULL;
static constexpr uint64_t kNanBits   = 0x7FF8000000000000ULL;
static constexpr uint64_t kInfBits   = 0x7FF0000000000000ULL;
static constexpr uint64_t kMantMask  = 0xFFFFFFFFFFFFFULL;

__global__ __launch_bounds__(256) void spike_fp64_sqrt_kernel(
    const float* __restrict__ x, float* __restrict__ out, int rows) {
  const int lane   = threadIdx.x & 63;
  const int waveId = (int)blockIdx.x * 4 + (threadIdx.x >> 6);
  const long long waveRow0 = (long long)waveId * 64;
  const int col = lane ^ 63;   // lane j loads pulse (63-j): ballot bit j == MSB-first bit j

  // ---- pack: 64 rows per wave; batched loads for memory-level parallelism ----
  uint64_t u = 0;
  const bool fullWave = (waveRow0 + 64) <= (long long)rows;
  if (fullWave) {
    const float* base = x + waveRow0 * 64 + col;
#pragma unroll
    for (int b = 0; b < 2; ++b) {
      float v[32];
#pragma unroll
      for (int k = 0; k < 32; ++k) v[k] = base[(b * 32 + k) * 64];   // 32 loads in flight
#pragma unroll
      for (int k = 0; k < 32; ++k) {
        unsigned long long m = __ballot(v[k] > 0.5f);
        if (lane == b * 32 + k) u = m;
      }
    }
  } else {
#pragma unroll
    for (int rr = 0; rr < 64; ++rr) {
      const long long row = waveRow0 + rr;
      float v = (row < (long long)rows) ? x[row * 64 + col] : 0.0f;
      unsigned long long m = __ballot(v > 0.5f);
      if (lane == rr) u = m;
    }
  }

  // ---- per-lane fp64 sqrt, bit-exact vs reference ----
  const double f = __longlong_as_double((long long)u);

  const int e_x    = (int)((u >> 52) & 0x7FF);
  const int e_real = e_x - 1023;                       // 11-bit two's complement
  const long long e_half = ((long long)e_real) >> 1;   // arithmetic shift = floor/2
  const uint64_t mant = ((e_real & 1) != 0) ? kSqrt2Mant : 0ULL;
  const uint64_t ybits = (((uint64_t)(e_half + 1023)) << 52) | mant;
  double y = __longlong_as_double((long long)ybits);

#pragma unroll
  for (int it = 0; it < 12; ++it) {
    y = 0.5 * (y + f / y);                             // IEEE fp64, no contraction
  }

  uint64_t r = (uint64_t)__double_as_longlong(y);
  const bool is_neg    = (u >> 63) != 0;
  const bool m_any     = (u & kMantMask) != 0;
  const bool e_all_one = (e_x == 0x7FF);
  const bool e_is_zero = (e_x == 0);
  if (is_neg) r = kNanBits;                            // same override order as ref
  if (e_all_one && m_any) r = kNanBits;
  if (e_all_one && !m_any && !is_neg) r = kInfBits;
  if (e_is_zero && !m_any) r = 0ULL;

  // ---- unpack: 4 rows / iteration, float4 stores ----
  const long long rl = (long long)r;
#pragma unroll
  for (int j = 0; j < 16; ++j) {
    const int srcRow = 4 * j + (lane >> 4);            // 0..63 within the wave
    const uint64_t b = (uint64_t)__shfl(rl, srcRow, 64);
    const int c0 = (lane & 15) * 4;                    // column of float4
    float4 o;
    o.x = (float)((b >> (63 - c0)) & 1ULL);
    o.y = (float)((b >> (62 - c0)) & 1ULL);
    o.z = (float)((b >> (61 - c0)) & 1ULL);
    o.w = (float)((b >> (60 - c0)) & 1ULL);
    const long long row = waveRow0 + srcRow;
    if (row < (long long)rows) {
      *reinterpret_cast<float4*>(out + row * 64 + c0) = o;
    }
  }
}

extern "C" void kernel_launch(void* const* d_in, const int* in_sizes, int n_in,
                              void* d_out, int out_size, void* d_ws, size_t ws_size,
                              hipStream_t stream) {
  const float* x = (const float*)d_in[0];
  float* out = (float*)d_out;
  const int rows = in_sizes[0] / 64;                   // 64 pulses per fp64
  const int rowsPerBlock = 256;                        // 4 waves * 64 rows
  const int grid = (rows + rowsPerBlock - 1) / rowsPerBlock;
  spike_fp64_sqrt_kernel<<<grid, 256, 0, stream>>>(x, out, rows);
}